// Round 21
// baseline (685.615 us; speedup 1.0000x reference)
//
#include <hip/hip_runtime.h>

typedef _Float16 f16;
typedef __fp16 hf2 __attribute__((ext_vector_type(2)));
typedef _Float16 f16x4 __attribute__((ext_vector_type(4)));
typedef _Float16 f16x8 __attribute__((ext_vector_type(8)));
typedef float f32x4 __attribute__((ext_vector_type(4)));

typedef const __attribute__((address_space(1))) unsigned int guint;
typedef __attribute__((address_space(3))) unsigned int luint;
__device__ __forceinline__ void gl_lds16(const void* g, void* l) {
    __builtin_amdgcn_global_load_lds((guint*)g, (luint*)l, 16, 0, 0);
}
template <int N>
__device__ __forceinline__ void vmwait() {
    if constexpr (N == 8)       asm volatile("s_waitcnt vmcnt(8)" ::: "memory");
    else if constexpr (N == 6)  asm volatile("s_waitcnt vmcnt(6)" ::: "memory");
    else if constexpr (N == 4)  asm volatile("s_waitcnt vmcnt(4)" ::: "memory");
    else                        asm volatile("s_waitcnt vmcnt(0)" ::: "memory");
}
__device__ __forceinline__ void barrier_raw() { __builtin_amdgcn_s_barrier(); __builtin_amdgcn_sched_barrier(0); }
__device__ __forceinline__ void lgkm0() { asm volatile("s_waitcnt lgkmcnt(0)" ::: "memory"); }

__device__ __forceinline__ f16x8 pack8(float4 x0, float4 x1) {
    hf2 p0 = __builtin_amdgcn_cvt_pkrtz(x0.x, x0.y);
    hf2 p1 = __builtin_amdgcn_cvt_pkrtz(x0.z, x0.w);
    hf2 p2 = __builtin_amdgcn_cvt_pkrtz(x1.x, x1.y);
    hf2 p3 = __builtin_amdgcn_cvt_pkrtz(x1.z, x1.w);
    f16x8 h;
    h[0] = (f16)p0[0]; h[1] = (f16)p0[1]; h[2] = (f16)p1[0]; h[3] = (f16)p1[1];
    h[4] = (f16)p2[0]; h[5] = (f16)p2[1]; h[6] = (f16)p3[0]; h[7] = (f16)p3[1];
    return h;
}

// ---------------- K0: convert + transpose 5 weight matrices (512x512) to f16 ----------------
__global__ __launch_bounds__(256) void wconv(const float* w0, const float* w1, const float* w2,
                                             const float* w3, const float* w4, f16* dst) {
    const float* src;
    switch (blockIdx.z) { case 0: src = w0; break; case 1: src = w1; break;
                          case 2: src = w2; break; case 3: src = w3; break; default: src = w4; }
    __shared__ float tile[32][33];
    int k0 = blockIdx.x * 32, n0 = blockIdx.y * 32;
    int t = threadIdx.x;
    int r = t >> 3, c4 = (t & 7) * 4;
    float4 v = *(const float4*)(src + (k0 + r) * 512 + n0 + c4);
    tile[r][c4 + 0] = v.x; tile[r][c4 + 1] = v.y; tile[r][c4 + 2] = v.z; tile[r][c4 + 3] = v.w;
    __syncthreads();
    f16x4 o;
    o[0] = (f16)tile[c4 + 0][r]; o[1] = (f16)tile[c4 + 1][r];
    o[2] = (f16)tile[c4 + 2][r]; o[3] = (f16)tile[c4 + 3][r];
    *(f16x4*)(dst + (size_t)blockIdx.z * 262144 + (n0 + r) * 512 + k0 + c4) = o;
}

// ---------------- K1a (QKV, fp32-A): 8ph skeleton + reg-staged A conversion + LDS-coalesced epilogue ----------------
__global__ __launch_bounds__(512, 2) void gemm_rs(const float* __restrict__ A,
                                                  const f16* __restrict__ Bt,
                                                  const float* __restrict__ bias,
                                                  f16* __restrict__ Cp) {
    constexpr int BUFSZ = 32768;   // A f16 16KB + B f16 16KB
    __shared__ __align__(16) char smem[4 * BUFSZ];

    const int cpx = gridDim.x >> 3;
    const int orig = blockIdx.x;
    const int wgid = (orig & 7) * cpx + (orig >> 3);
    const int by = wgid & 1, bx = wgid >> 1;
    const int r0 = bx * 256, c0 = by * 256;

    const int t = threadIdx.x, j = t & 63, w = t >> 6;
    const int lr = j & 15, lq = j >> 4;
    const int wr = (w >> 2) * 128, wc = (w & 3) * 64;

    const float* aS = A + (size_t)(r0 + (t >> 1)) * 512 + (t & 1) * 16;
    const int awRow = t >> 1;
    const int awS = (t >> 2) & 3;
    const int awc = (t & 1) * 2;
    const int aw0 = awRow * 64 + ((awc ^ awS) << 4);
    const int aw1 = awRow * 64 + (((awc + 1) ^ awS) << 4);

    const int srow = t >> 2;
    const int sblk = (t & 3) ^ ((t >> 3) & 3);
    const f16* bS = Bt + (size_t)(c0 + srow) * 512 + sblk * 8;
    const int dstT = t * 16;

    int aoff[8], boff[4];
#pragma unroll
    for (int m = 0; m < 8; m++) {
        int row = wr + m * 16 + lr;
        aoff[m] = row * 64 + ((lq ^ ((row >> 1) & 3)) << 4);
    }
#pragma unroll
    for (int nb = 0; nb < 4; nb++) {
        int row = wc + nb * 16 + lr;
        boff[nb] = 16384 + row * 64 + ((lq ^ ((row >> 1) & 3)) << 4);
    }

    f32x4 acc[8][4] = {};
    float4 rgA[4], rgB[4];

    auto loadTo = [&](int kt, float4* rg) {
        const float* p = aS + kt * 32;
        rg[0] = *(const float4*)p;
        rg[1] = *(const float4*)(p + 4);
        rg[2] = *(const float4*)(p + 8);
        rg[3] = *(const float4*)(p + 12);
    };
    auto writeA = [&](const float4* rg, int buf) {
        char* base = smem + buf * BUFSZ;
        *(f16x8*)(base + aw0) = pack8(rg[0], rg[1]);
        *(f16x8*)(base + aw1) = pack8(rg[2], rg[3]);
    };
    auto stageB = [&](int kt) {
        char* d = smem + (kt & 3) * BUFSZ + 16384 + dstT;
        const f16* s = bS + kt * 32;
        gl_lds16(s, d);
        gl_lds16(s + 65536, d + 8192);
    };

#define PHASE_A(kt, bfr)                                                    \
    do {                                                                    \
        const char* sb_ = smem + ((kt) & 3) * BUFSZ;                        \
        f16x8 afr[4];                                                       \
        _Pragma("unroll")                                                   \
        for (int nb = 0; nb < 4; nb++) bfr[nb] = *(const f16x8*)(sb_ + boff[nb]); \
        _Pragma("unroll")                                                   \
        for (int m = 0; m < 4; m++) afr[m] = *(const f16x8*)(sb_ + aoff[m]); \
        __builtin_amdgcn_s_setprio(1);                                      \
        _Pragma("unroll")                                                   \
        for (int m = 0; m < 4; m++)                                         \
            _Pragma("unroll")                                               \
            for (int nb = 0; nb < 4; nb++)                                  \
                acc[m][nb] = __builtin_amdgcn_mfma_f32_16x16x32_f16(afr[m], bfr[nb], acc[m][nb], 0, 0, 0); \
        __builtin_amdgcn_s_setprio(0);                                      \
    } while (0)

#define PHASE_B(kt, bfr)                                                    \
    do {                                                                    \
        const char* sb_ = smem + ((kt) & 3) * BUFSZ;                        \
        f16x8 afr2[4];                                                      \
        _Pragma("unroll")                                                   \
        for (int m = 0; m < 4; m++) afr2[m] = *(const f16x8*)(sb_ + aoff[m + 4]); \
        __builtin_amdgcn_s_setprio(1);                                      \
        _Pragma("unroll")                                                   \
        for (int m = 0; m < 4; m++)                                         \
            _Pragma("unroll")                                               \
            for (int nb = 0; nb < 4; nb++)                                  \
                acc[m + 4][nb] = __builtin_amdgcn_mfma_f32_16x16x32_f16(afr2[m], bfr[nb], acc[m + 4][nb], 0, 0, 0); \
        __builtin_amdgcn_s_setprio(0);                                      \
    } while (0)

    loadTo(0, rgA);
    stageB(0); stageB(1);
    loadTo(1, rgB);
    stageB(2);
    vmwait<8>();
    __builtin_amdgcn_sched_barrier(0);
    writeA(rgA, 0);
    lgkm0();
    barrier_raw();

#pragma unroll 1
    for (int k2 = 0; k2 < 8; ++k2) {
        {   // even sub-iter
            const int kt = 2 * k2;
            if (k2 <= 6) loadTo(kt + 2, rgA);
            if (k2 <= 6) vmwait<6>(); else vmwait<0>();
            __builtin_amdgcn_sched_barrier(0);
            writeA(rgB, (kt + 1) & 3);
            f16x8 bfr[4];
            PHASE_A(kt, bfr);
            barrier_raw();
            if (k2 <= 6) stageB(kt + 3);
            PHASE_B(kt, bfr);
            lgkm0();
            barrier_raw();
        }
        {   // odd sub-iter
            const int kt = 2 * k2 + 1;
            if (k2 <= 6) loadTo(kt + 2, rgB);
            if (k2 <= 6) vmwait<6>(); else vmwait<0>();
            __builtin_amdgcn_sched_barrier(0);
            if (k2 <= 6) writeA(rgA, (kt + 1) & 3);
            f16x8 bfr[4];
            PHASE_A(kt, bfr);
            barrier_raw();
            if (k2 <= 5) stageB(kt + 3);
            PHASE_B(kt, bfr);
            lgkm0();
            barrier_raw();
        }
    }
#undef PHASE_A
#undef PHASE_B

    // LDS-coalesced epilogue (proven R20): [256 rows][512B], blk ^= (row&31)
#pragma unroll
    for (int nb = 0; nb < 4; nb++) {
        int col = wc + nb * 16 + lr;
        float b = bias[c0 + col];
#pragma unroll
        for (int m = 0; m < 8; m++) {
#pragma unroll
            for (int r = 0; r < 4; r++) {
                float v = fmaxf(acc[m][nb][r] + b, 0.0f);
                int row = wr + m * 16 + lq * 4 + r;
                int pblk = (col >> 3) ^ (row & 31);
                *(f16*)(smem + row * 512 + (pblk << 4) + (col & 7) * 2) = (f16)v;
            }
        }
    }
    lgkm0();
    barrier_raw();
#pragma unroll
    for (int i = 0; i < 16; i++) {
        int ci = i * 512 + t;
        int row = ci >> 5, blk = ci & 31;
        int pblk = blk ^ (row & 31);
        f16x8 vle = *(const f16x8*)(smem + row * 512 + (pblk << 4));
        *(f16x8*)(Cp + (size_t)(r0 + row) * 512 + c0 + blk * 8) = vle;
    }
}

// ---------------- K1b (FFN, f16-A): 8-phase counted-vmcnt GEMM + LDS-coalesced epilogues ----------------
template <bool RELU, bool O16>
__global__ __launch_bounds__(512, 2) void gemm_8ph(const f16* __restrict__ A,
                                                   const f16* __restrict__ Bt,
                                                   const float* __restrict__ bias,
                                                   void* __restrict__ Cp) {
    constexpr int BUFSZ = 32768;
    __shared__ __align__(16) char smem[4 * BUFSZ];

    const int cpx = gridDim.x >> 3;
    const int orig = blockIdx.x;
    const int wgid = (orig & 7) * cpx + (orig >> 3);
    const int by = wgid & 1;
    const int bx = wgid >> 1;
    const int r0 = bx * 256, c0 = by * 256;

    const int t = threadIdx.x;
    const int j = t & 63, w = t >> 6;
    const int lr = j & 15, lq = j >> 4;
    const int wr = (w >> 2) * 128, wc = (w & 3) * 64;

    const int srow = t >> 2;
    const int sblk = (t & 3) ^ ((t >> 3) & 3);
    const f16* aS = A  + (size_t)(r0 + srow) * 512 + sblk * 8;
    const f16* bS = Bt + (size_t)(c0 + srow) * 512 + sblk * 8;
    const int dstT = t * 16;

    int aoff[8], boff[4];
#pragma unroll
    for (int m = 0; m < 8; m++) {
        int row = wr + m * 16 + lr;
        aoff[m] = row * 64 + ((lq ^ ((row >> 1) & 3)) << 4);
    }
#pragma unroll
    for (int nb = 0; nb < 4; nb++) {
        int row = wc + nb * 16 + lr;
        boff[nb] = 16384 + row * 64 + ((lq ^ ((row >> 1) & 3)) << 4);
    }

    f32x4 acc[8][4] = {};

    auto stageA = [&](int kt) {
        char* d = smem + (kt & 3) * BUFSZ + dstT;
        const f16* s = aS + kt * 32;
        gl_lds16(s, d);
        gl_lds16(s + 65536, d + 8192);
    };
    auto stageB = [&](int kt) {
        char* d = smem + (kt & 3) * BUFSZ + 16384 + dstT;
        const f16* s = bS + kt * 32;
        gl_lds16(s, d);
        gl_lds16(s + 65536, d + 8192);
    };

    stageA(0); stageB(0); stageA(1); stageB(1); stageA(2); stageB(2);

#pragma unroll 1
    for (int kt = 0; kt < 16; ++kt) {
        const char* sb = smem + (kt & 3) * BUFSZ;
        if (kt <= 13)      vmwait<8>();
        else if (kt == 14) vmwait<4>();
        else               vmwait<0>();
        barrier_raw();
        if (kt < 13) stageA(kt + 3);
        f16x8 bfr[4], afr[4];
#pragma unroll
        for (int nb = 0; nb < 4; nb++) bfr[nb] = *(const f16x8*)(sb + boff[nb]);
#pragma unroll
        for (int m = 0; m < 4; m++) afr[m] = *(const f16x8*)(sb + aoff[m]);
        __builtin_amdgcn_s_setprio(1);
#pragma unroll
        for (int m = 0; m < 4; m++)
#pragma unroll
            for (int nb = 0; nb < 4; nb++)
                acc[m][nb] = __builtin_amdgcn_mfma_f32_16x16x32_f16(afr[m], bfr[nb], acc[m][nb], 0, 0, 0);
        __builtin_amdgcn_s_setprio(0);
        barrier_raw();
        if (kt < 13) stageB(kt + 3);
        f16x8 afr2[4];
#pragma unroll
        for (int m = 0; m < 4; m++) afr2[m] = *(const f16x8*)(sb + aoff[m + 4]);
        __builtin_amdgcn_s_setprio(1);
#pragma unroll
        for (int m = 0; m < 4; m++)
#pragma unroll
            for (int nb = 0; nb < 4; nb++)
                acc[m + 4][nb] = __builtin_amdgcn_mfma_f32_16x16x32_f16(afr2[m], bfr[nb], acc[m + 4][nb], 0, 0, 0);
        __builtin_amdgcn_s_setprio(0);
    }

    if (O16) {
        // f16 out: [256 rows][512B] swizzled stage, then 16B/lane coalesced stores
#pragma unroll
        for (int nb = 0; nb < 4; nb++) {
            int col = wc + nb * 16 + lr;
            float b = bias[c0 + col];
#pragma unroll
            for (int m = 0; m < 8; m++) {
#pragma unroll
                for (int r = 0; r < 4; r++) {
                    float v = acc[m][nb][r] + b;
                    if (RELU) v = fmaxf(v, 0.0f);
                    int row = wr + m * 16 + lq * 4 + r;
                    int pblk = (col >> 3) ^ (row & 31);
                    *(f16*)(smem + row * 512 + (pblk << 4) + (col & 7) * 2) = (f16)v;
                }
            }
        }
        lgkm0();
        barrier_raw();
#pragma unroll
        for (int i = 0; i < 16; i++) {
            int ci = i * 512 + t;
            int row = ci >> 5, blk = ci & 31;
            int pblk = blk ^ (row & 31);
            f16x8 vle = *(const f16x8*)(smem + row * 512 + (pblk << 4));
            *(f16x8*)((f16*)Cp + (size_t)(r0 + row) * 512 + c0 + blk * 8) = vle;
        }
    } else {
        // fp32 out: two passes of 128 rows x 1KB = 128KB. Wave group p owns rows [128p, 128p+128).
#pragma unroll 1
        for (int p = 0; p < 2; p++) {
            barrier_raw();
            if ((w >> 2) == p) {
#pragma unroll
                for (int nb = 0; nb < 4; nb++) {
                    int col = wc + nb * 16 + lr;
                    float b = bias[c0 + col];
#pragma unroll
                    for (int m = 0; m < 8; m++) {
#pragma unroll
                        for (int r = 0; r < 4; r++) {
                            float v = acc[m][nb][r] + b;
                            if (RELU) v = fmaxf(v, 0.0f);
                            int lrow = m * 16 + lq * 4 + r;           // 0..127
                            int pblk = (col >> 2) ^ (lrow & 63);
                            *(float*)(smem + lrow * 1024 + (pblk << 4) + (col & 3) * 4) = v;
                        }
                    }
                }
            }
            lgkm0();
            barrier_raw();
#pragma unroll
            for (int i = 0; i < 16; i++) {
                int ci = i * 512 + t;
                int lrow = ci >> 6, blk = ci & 63;
                int pblk = blk ^ (lrow & 63);
                float4 vle = *(const float4*)(smem + lrow * 1024 + (pblk << 4));
                *(float4*)((float*)Cp + (size_t)(r0 + p * 128 + lrow) * 512 + c0 + blk * 4) = vle;
            }
        }
    }
}

// ---------------- K2: attention per (b,h,n). 1 wave/block. LDS-coalesced O store. ----------------
__global__ __launch_bounds__(64) void attn_kernel(const f16* __restrict__ q,
                                                  const f16* __restrict__ k,
                                                  const f16* __restrict__ v,
                                                  f16* __restrict__ out) {
    const int h = blockIdx.x, n = blockIdx.y, b = blockIdx.z;
    __shared__ f16 sQ[48 * 72];
    __shared__ f16 sK[48 * 72];
    __shared__ f16 sP[48 * 72];
    __shared__ f16 sVt[64 * 72];
    const int l = threadIdx.x, lr = l & 15, lq = l >> 4;
    const size_t rowstride = 256 * 512;
    const size_t base = ((size_t)(b * 48) * 256 + n) * 512 + h * 64;

    const int pr = l >> 3, pc = (l & 7) * 8;
#pragma unroll
    for (int pass = 0; pass < 6; pass++) {
        int row = pass * 8 + pr;
        size_t g = base + (size_t)row * rowstride + pc;
        f16x8 qv = *(const f16x8*)(q + g);
        f16x8 kv = *(const f16x8*)(k + g);
        f16x8 vv = *(const f16x8*)(v + g);
        *(f16x8*)&sQ[row * 72 + pc] = qv;
        *(f16x8*)&sK[row * 72 + pc] = kv;
#pragma unroll
        for (int jj = 0; jj < 8; jj++) sVt[(pc + jj) * 72 + row] = vv[jj];
    }
    {
        f16x8 z = {};
        *(f16x8*)&sVt[l * 72 + 48] = z;
        *(f16x8*)&sVt[l * 72 + 56] = z;
        if (l < 48) { *(f16x8*)&sP[l * 72 + 48] = z; *(f16x8*)&sP[l * 72 + 56] = z; }
    }
    __syncthreads();

    f32x4 s[3][3] = {};
#pragma unroll
    for (int ks = 0; ks < 2; ks++) {
        f16x8 aq[3], bk[3];
#pragma unroll
        for (int m = 0; m < 3; m++)  aq[m] = *(const f16x8*)&sQ[(m * 16 + lr) * 72 + ks * 32 + lq * 8];
#pragma unroll
        for (int nb = 0; nb < 3; nb++) bk[nb] = *(const f16x8*)&sK[(nb * 16 + lr) * 72 + ks * 32 + lq * 8];
#pragma unroll
        for (int m = 0; m < 3; m++)
#pragma unroll
            for (int nb = 0; nb < 3; nb++)
                s[m][nb] = __builtin_amdgcn_mfma_f32_16x16x32_f16(aq[m], bk[nb], s[m][nb], 0, 0, 0);
    }

#pragma unroll
    for (int m = 0; m < 3; m++) {
#pragma unroll
        for (int r = 0; r < 4; r++) {
            float a0 = s[m][0][r] * 0.125f, a1 = s[m][1][r] * 0.125f, a2 = s[m][2][r] * 0.125f;
            float mx = fmaxf(a0, fmaxf(a1, a2));
#pragma unroll
            for (int d = 1; d < 16; d <<= 1) mx = fmaxf(mx, __shfl_xor(mx, d));
            float e0 = __expf(a0 - mx), e1 = __expf(a1 - mx), e2 = __expf(a2 - mx);
            float sm = e0 + e1 + e2;
#pragma unroll
            for (int d = 1; d < 16; d <<= 1) sm += __shfl_xor(sm, d);
            float inv = 1.0f / sm;
            int row = m * 16 + lq * 4 + r;
            sP[row * 72 + 0  + lr] = (f16)(e0 * inv);
            sP[row * 72 + 16 + lr] = (f16)(e1 * inv);
            sP[row * 72 + 32 + lr] = (f16)(e2 * inv);
        }
    }
    __syncthreads();

    f32x4 o[3][4] = {};
#pragma unroll
    for (int ks = 0; ks < 2; ks++) {
        f16x8 ap[3], bvv[4];
#pragma unroll
        for (int m = 0; m < 3; m++)  ap[m] = *(const f16x8*)&sP[(m * 16 + lr) * 72 + ks * 32 + lq * 8];
#pragma unroll
        for (int nb = 0; nb < 4; nb++) bvv[nb] = *(const f16x8*)&sVt[(nb * 16 + lr) * 72 + ks * 32 + lq * 8];
#pragma unroll
        for (int m = 0; m < 3; m++)
#pragma unroll
            for (int nb = 0; nb < 4; nb++)
                o[m][nb] = __builtin_amdgcn_mfma_f32_16x16x32_f16(ap[m], bvv[nb], o[m][nb], 0, 0, 0);
    }

    // LDS-coalesced O store: stage [48 rows][128B] into sQ (free after QK^T), blk ^= (row&7)
    {
        char* so = (char*)sQ;
#pragma unroll
        for (int m = 0; m < 3; m++)
#pragma unroll
            for (int nb = 0; nb < 4; nb++)
#pragma unroll
                for (int r = 0; r < 4; r++) {
                    int row = m * 16 + lq * 4 + r;
                    int col = nb * 16 + lr;
                    int pblk = (col >> 3) ^ (row & 7);
                    *(f16*)(so + row * 128 + (pblk << 4) + (col & 7) * 2) = (f16)o[m][nb][r];
                }
        __syncthreads();
#pragma unroll
        for (int i = 0; i < 6; i++) {
            int ci = i * 64 + l;
            int row = ci >> 3, blk = ci & 7;
            int pblk = blk ^ (row & 7);
            f16x8 vle = *(const f16x8*)(so + row * 128 + (pblk << 4));
            *(f16x8*)(out + base + (size_t)row * rowstride + blk * 8) = vle;
        }
    }
}

// ---------------- launch ----------------
extern "C" void kernel_launch(void* const* d_in, const int* in_sizes, int n_in,
                              void* d_out, int out_size, void* d_ws, size_t ws_size,
                              hipStream_t stream) {
    const float* X    = (const float*)d_in[0];
    const float* STEP = (const float*)d_in[1];
    const float* STEQ = (const float*)d_in[2];
    const float* Wq   = (const float*)d_in[3];
    const float* bq   = (const float*)d_in[4];
    const float* Wk   = (const float*)d_in[5];
    const float* bk   = (const float*)d_in[6];
    const float* Wv   = (const float*)d_in[7];
    const float* bv   = (const float*)d_in[8];
    const float* W1   = (const float*)d_in[9];
    const float* b1   = (const float*)d_in[10];
    const float* W2   = (const float*)d_in[11];
    const float* b2   = (const float*)d_in[12];
    float* out = (float*)d_out;

    const size_t MROWS = 98304;           // B*TQ*N = 8*48*256
    const size_t MBUF  = MROWS * 512;
    f16* ws  = (f16*)d_ws;
    f16* Wqt = ws;                        // 512*512 each
    f16* Wkt = ws + 262144;
    f16* Wvt = ws + 524288;
    f16* W1t = ws + 786432;
    f16* W2t = ws + 1048576;
    f16* qb  = ws + 1310720;              // MBUF f16 each
    f16* kb  = qb + MBUF;
    f16* vb  = kb + MBUF;
    f16* hb  = kb;                        // FFN hidden reuses k buffer (after attn)

    wconv<<<dim3(16, 16, 5), 256, 0, stream>>>(Wq, Wk, Wv, W1, W2, ws);

    gemm_rs<<<768, 512, 0, stream>>>(STEQ, Wqt, bq, qb);
    gemm_rs<<<768, 512, 0, stream>>>(STEP, Wkt, bk, kb);
    gemm_rs<<<768, 512, 0, stream>>>(X,    Wvt, bv, vb);

    attn_kernel<<<dim3(8, 256, 8), 64, 0, stream>>>(qb, kb, vb, qb);

    gemm_8ph<true,  true ><<<768, 512, 0, stream>>>(qb, W1t, b1, hb);
    gemm_8ph<false, false><<<768, 512, 0, stream>>>(hb, W2t, b2, out);
}

// Round 22
// 579.703 us; speedup vs baseline: 1.1827x; 1.1827x over previous
//
#include <hip/hip_runtime.h>

typedef _Float16 f16;
typedef __fp16 hf2 __attribute__((ext_vector_type(2)));
typedef _Float16 f16x4 __attribute__((ext_vector_type(4)));
typedef _Float16 f16x8 __attribute__((ext_vector_type(8)));
typedef float f32x4 __attribute__((ext_vector_type(4)));

typedef const __attribute__((address_space(1))) unsigned int guint;
typedef __attribute__((address_space(3))) unsigned int luint;
__device__ __forceinline__ void gl_lds16(const void* g, void* l) {
    __builtin_amdgcn_global_load_lds((guint*)g, (luint*)l, 16, 0, 0);
}
template <int N>
__device__ __forceinline__ void vmwait() {
    if constexpr (N == 8)       asm volatile("s_waitcnt vmcnt(8)" ::: "memory");
    else if constexpr (N == 6)  asm volatile("s_waitcnt vmcnt(6)" ::: "memory");
    else if constexpr (N == 4)  asm volatile("s_waitcnt vmcnt(4)" ::: "memory");
    else                        asm volatile("s_waitcnt vmcnt(0)" ::: "memory");
}
__device__ __forceinline__ void barrier_raw() { __builtin_amdgcn_s_barrier(); __builtin_amdgcn_sched_barrier(0); }
__device__ __forceinline__ void lgkm0() { asm volatile("s_waitcnt lgkmcnt(0)" ::: "memory"); }

__device__ __forceinline__ f16x8 pack8(float4 x0, float4 x1) {
    hf2 p0 = __builtin_amdgcn_cvt_pkrtz(x0.x, x0.y);
    hf2 p1 = __builtin_amdgcn_cvt_pkrtz(x0.z, x0.w);
    hf2 p2 = __builtin_amdgcn_cvt_pkrtz(x1.x, x1.y);
    hf2 p3 = __builtin_amdgcn_cvt_pkrtz(x1.z, x1.w);
    f16x8 h;
    h[0] = (f16)p0[0]; h[1] = (f16)p0[1]; h[2] = (f16)p1[0]; h[3] = (f16)p1[1];
    h[4] = (f16)p2[0]; h[5] = (f16)p2[1]; h[6] = (f16)p3[0]; h[7] = (f16)p3[1];
    return h;
}

// ---------------- K0: convert + transpose 5 weight matrices (512x512) to f16 ----------------
__global__ __launch_bounds__(256) void wconv(const float* w0, const float* w1, const float* w2,
                                             const float* w3, const float* w4, f16* dst) {
    const float* src;
    switch (blockIdx.z) { case 0: src = w0; break; case 1: src = w1; break;
                          case 2: src = w2; break; case 3: src = w3; break; default: src = w4; }
    __shared__ float tile[32][33];
    int k0 = blockIdx.x * 32, n0 = blockIdx.y * 32;
    int t = threadIdx.x;
    int r = t >> 3, c4 = (t & 7) * 4;
    float4 v = *(const float4*)(src + (k0 + r) * 512 + n0 + c4);
    tile[r][c4 + 0] = v.x; tile[r][c4 + 1] = v.y; tile[r][c4 + 2] = v.z; tile[r][c4 + 3] = v.w;
    __syncthreads();
    f16x4 o;
    o[0] = (f16)tile[c4 + 0][r]; o[1] = (f16)tile[c4 + 1][r];
    o[2] = (f16)tile[c4 + 2][r]; o[3] = (f16)tile[c4 + 3][r];
    *(f16x4*)(dst + (size_t)blockIdx.z * 262144 + (n0 + r) * 512 + k0 + c4) = o;
}

// ---------------- K1a (QKV, fp32-A): 8ph skeleton + reg-staged A conversion + LDS-coalesced epilogue ----------------
__global__ __launch_bounds__(512, 2) void gemm_rs(const float* __restrict__ A,
                                                  const f16* __restrict__ Bt,
                                                  const float* __restrict__ bias,
                                                  f16* __restrict__ Cp) {
    constexpr int BUFSZ = 32768;   // A f16 16KB + B f16 16KB
    __shared__ __align__(16) char smem[4 * BUFSZ];

    const int cpx = gridDim.x >> 3;
    const int orig = blockIdx.x;
    const int wgid = (orig & 7) * cpx + (orig >> 3);
    const int by = wgid & 1, bx = wgid >> 1;
    const int r0 = bx * 256, c0 = by * 256;

    const int t = threadIdx.x, j = t & 63, w = t >> 6;
    const int lr = j & 15, lq = j >> 4;
    const int wr = (w >> 2) * 128, wc = (w & 3) * 64;

    const float* aS = A + (size_t)(r0 + (t >> 1)) * 512 + (t & 1) * 16;
    const int awRow = t >> 1;
    const int awS = (t >> 2) & 3;
    const int awc = (t & 1) * 2;
    const int aw0 = awRow * 64 + ((awc ^ awS) << 4);
    const int aw1 = awRow * 64 + (((awc + 1) ^ awS) << 4);

    const int srow = t >> 2;
    const int sblk = (t & 3) ^ ((t >> 3) & 3);
    const f16* bS = Bt + (size_t)(c0 + srow) * 512 + sblk * 8;
    const int dstT = t * 16;

    int aoff[8], boff[4];
#pragma unroll
    for (int m = 0; m < 8; m++) {
        int row = wr + m * 16 + lr;
        aoff[m] = row * 64 + ((lq ^ ((row >> 1) & 3)) << 4);
    }
#pragma unroll
    for (int nb = 0; nb < 4; nb++) {
        int row = wc + nb * 16 + lr;
        boff[nb] = 16384 + row * 64 + ((lq ^ ((row >> 1) & 3)) << 4);
    }

    f32x4 acc[8][4] = {};
    float4 rgA[4], rgB[4];

    auto loadTo = [&](int kt, float4* rg) {
        const float* p = aS + kt * 32;
        rg[0] = *(const float4*)p;
        rg[1] = *(const float4*)(p + 4);
        rg[2] = *(const float4*)(p + 8);
        rg[3] = *(const float4*)(p + 12);
    };
    auto writeA = [&](const float4* rg, int buf) {
        char* base = smem + buf * BUFSZ;
        *(f16x8*)(base + aw0) = pack8(rg[0], rg[1]);
        *(f16x8*)(base + aw1) = pack8(rg[2], rg[3]);
    };
    auto stageB = [&](int kt) {
        char* d = smem + (kt & 3) * BUFSZ + 16384 + dstT;
        const f16* s = bS + kt * 32;
        gl_lds16(s, d);
        gl_lds16(s + 65536, d + 8192);
    };

#define PHASE_A(kt, bfr)                                                    \
    do {                                                                    \
        const char* sb_ = smem + ((kt) & 3) * BUFSZ;                        \
        f16x8 afr[4];                                                       \
        _Pragma("unroll")                                                   \
        for (int nb = 0; nb < 4; nb++) bfr[nb] = *(const f16x8*)(sb_ + boff[nb]); \
        _Pragma("unroll")                                                   \
        for (int m = 0; m < 4; m++) afr[m] = *(const f16x8*)(sb_ + aoff[m]); \
        __builtin_amdgcn_s_setprio(1);                                      \
        _Pragma("unroll")                                                   \
        for (int m = 0; m < 4; m++)                                         \
            _Pragma("unroll")                                               \
            for (int nb = 0; nb < 4; nb++)                                  \
                acc[m][nb] = __builtin_amdgcn_mfma_f32_16x16x32_f16(afr[m], bfr[nb], acc[m][nb], 0, 0, 0); \
        __builtin_amdgcn_s_setprio(0);                                      \
    } while (0)

#define PHASE_B(kt, bfr)                                                    \
    do {                                                                    \
        const char* sb_ = smem + ((kt) & 3) * BUFSZ;                        \
        f16x8 afr2[4];                                                      \
        _Pragma("unroll")                                                   \
        for (int m = 0; m < 4; m++) afr2[m] = *(const f16x8*)(sb_ + aoff[m + 4]); \
        __builtin_amdgcn_s_setprio(1);                                      \
        _Pragma("unroll")                                                   \
        for (int m = 0; m < 4; m++)                                         \
            _Pragma("unroll")                                               \
            for (int nb = 0; nb < 4; nb++)                                  \
                acc[m + 4][nb] = __builtin_amdgcn_mfma_f32_16x16x32_f16(afr2[m], bfr[nb], acc[m + 4][nb], 0, 0, 0); \
        __builtin_amdgcn_s_setprio(0);                                      \
    } while (0)

    loadTo(0, rgA);
    stageB(0); stageB(1);
    loadTo(1, rgB);
    stageB(2);
    vmwait<8>();
    __builtin_amdgcn_sched_barrier(0);
    writeA(rgA, 0);
    lgkm0();
    barrier_raw();

#pragma unroll 1
    for (int k2 = 0; k2 < 8; ++k2) {
        {   // even sub-iter
            const int kt = 2 * k2;
            if (k2 <= 6) loadTo(kt + 2, rgA);
            if (k2 <= 6) vmwait<6>(); else vmwait<0>();
            __builtin_amdgcn_sched_barrier(0);
            writeA(rgB, (kt + 1) & 3);
            f16x8 bfr[4];
            PHASE_A(kt, bfr);
            barrier_raw();
            if (k2 <= 6) stageB(kt + 3);
            PHASE_B(kt, bfr);
            lgkm0();
            barrier_raw();
        }
        {   // odd sub-iter
            const int kt = 2 * k2 + 1;
            if (k2 <= 6) loadTo(kt + 2, rgB);
            if (k2 <= 6) vmwait<6>(); else vmwait<0>();
            __builtin_amdgcn_sched_barrier(0);
            if (k2 <= 6) writeA(rgA, (kt + 1) & 3);
            f16x8 bfr[4];
            PHASE_A(kt, bfr);
            barrier_raw();
            if (k2 <= 5) stageB(kt + 3);
            PHASE_B(kt, bfr);
            lgkm0();
            barrier_raw();
        }
    }
#undef PHASE_A
#undef PHASE_B

    // LDS-coalesced epilogue (proven R20): [256 rows][512B], blk ^= (row&31)
#pragma unroll
    for (int nb = 0; nb < 4; nb++) {
        int col = wc + nb * 16 + lr;
        float b = bias[c0 + col];
#pragma unroll
        for (int m = 0; m < 8; m++) {
#pragma unroll
            for (int r = 0; r < 4; r++) {
                float v = fmaxf(acc[m][nb][r] + b, 0.0f);
                int row = wr + m * 16 + lq * 4 + r;
                int pblk = (col >> 3) ^ (row & 31);
                *(f16*)(smem + row * 512 + (pblk << 4) + (col & 7) * 2) = (f16)v;
            }
        }
    }
    lgkm0();
    barrier_raw();
#pragma unroll
    for (int i = 0; i < 16; i++) {
        int ci = i * 512 + t;
        int row = ci >> 5, blk = ci & 31;
        int pblk = blk ^ (row & 31);
        f16x8 vle = *(const f16x8*)(smem + row * 512 + (pblk << 4));
        *(f16x8*)(Cp + (size_t)(r0 + row) * 512 + c0 + blk * 8) = vle;
    }
}

// ---------------- K1b (FFN, f16-A): 8-phase counted-vmcnt GEMM ----------------
// O16 (f16 out): LDS-coalesced epilogue (half-line fix, R20-proven).
// !O16 (fp32 out): ORIGINAL scalar epilogue -- 16 lanes x 4B = full 64B lines, already optimal;
//                  the R21 LDS variant spilled (VGPR cap 128) and regressed 76->209us.
template <bool RELU, bool O16>
__global__ __launch_bounds__(512, 2) void gemm_8ph(const f16* __restrict__ A,
                                                   const f16* __restrict__ Bt,
                                                   const float* __restrict__ bias,
                                                   void* __restrict__ Cp) {
    constexpr int BUFSZ = 32768;
    __shared__ __align__(16) char smem[4 * BUFSZ];

    const int cpx = gridDim.x >> 3;
    const int orig = blockIdx.x;
    const int wgid = (orig & 7) * cpx + (orig >> 3);
    const int by = wgid & 1;
    const int bx = wgid >> 1;
    const int r0 = bx * 256, c0 = by * 256;

    const int t = threadIdx.x;
    const int j = t & 63, w = t >> 6;
    const int lr = j & 15, lq = j >> 4;
    const int wr = (w >> 2) * 128, wc = (w & 3) * 64;

    const int srow = t >> 2;
    const int sblk = (t & 3) ^ ((t >> 3) & 3);
    const f16* aS = A  + (size_t)(r0 + srow) * 512 + sblk * 8;
    const f16* bS = Bt + (size_t)(c0 + srow) * 512 + sblk * 8;
    const int dstT = t * 16;

    int aoff[8], boff[4];
#pragma unroll
    for (int m = 0; m < 8; m++) {
        int row = wr + m * 16 + lr;
        aoff[m] = row * 64 + ((lq ^ ((row >> 1) & 3)) << 4);
    }
#pragma unroll
    for (int nb = 0; nb < 4; nb++) {
        int row = wc + nb * 16 + lr;
        boff[nb] = 16384 + row * 64 + ((lq ^ ((row >> 1) & 3)) << 4);
    }

    f32x4 acc[8][4] = {};

    auto stageA = [&](int kt) {
        char* d = smem + (kt & 3) * BUFSZ + dstT;
        const f16* s = aS + kt * 32;
        gl_lds16(s, d);
        gl_lds16(s + 65536, d + 8192);
    };
    auto stageB = [&](int kt) {
        char* d = smem + (kt & 3) * BUFSZ + 16384 + dstT;
        const f16* s = bS + kt * 32;
        gl_lds16(s, d);
        gl_lds16(s + 65536, d + 8192);
    };

    stageA(0); stageB(0); stageA(1); stageB(1); stageA(2); stageB(2);

#pragma unroll 1
    for (int kt = 0; kt < 16; ++kt) {
        const char* sb = smem + (kt & 3) * BUFSZ;
        if (kt <= 13)      vmwait<8>();
        else if (kt == 14) vmwait<4>();
        else               vmwait<0>();
        barrier_raw();
        if (kt < 13) stageA(kt + 3);
        f16x8 bfr[4], afr[4];
#pragma unroll
        for (int nb = 0; nb < 4; nb++) bfr[nb] = *(const f16x8*)(sb + boff[nb]);
#pragma unroll
        for (int m = 0; m < 4; m++) afr[m] = *(const f16x8*)(sb + aoff[m]);
        __builtin_amdgcn_s_setprio(1);
#pragma unroll
        for (int m = 0; m < 4; m++)
#pragma unroll
            for (int nb = 0; nb < 4; nb++)
                acc[m][nb] = __builtin_amdgcn_mfma_f32_16x16x32_f16(afr[m], bfr[nb], acc[m][nb], 0, 0, 0);
        __builtin_amdgcn_s_setprio(0);
        barrier_raw();
        if (kt < 13) stageB(kt + 3);
        f16x8 afr2[4];
#pragma unroll
        for (int m = 0; m < 4; m++) afr2[m] = *(const f16x8*)(sb + aoff[m + 4]);
        __builtin_amdgcn_s_setprio(1);
#pragma unroll
        for (int m = 0; m < 4; m++)
#pragma unroll
            for (int nb = 0; nb < 4; nb++)
                acc[m + 4][nb] = __builtin_amdgcn_mfma_f32_16x16x32_f16(afr2[m], bfr[nb], acc[m + 4][nb], 0, 0, 0);
        __builtin_amdgcn_s_setprio(0);
    }

    if (O16) {
        // f16 out: [256 rows][512B] swizzled stage, then 16B/lane coalesced stores
#pragma unroll
        for (int nb = 0; nb < 4; nb++) {
            int col = wc + nb * 16 + lr;
            float b = bias[c0 + col];
#pragma unroll
            for (int m = 0; m < 8; m++) {
#pragma unroll
                for (int r = 0; r < 4; r++) {
                    float v = acc[m][nb][r] + b;
                    if (RELU) v = fmaxf(v, 0.0f);
                    int row = wr + m * 16 + lq * 4 + r;
                    int pblk = (col >> 3) ^ (row & 31);
                    *(f16*)(smem + row * 512 + (pblk << 4) + (col & 7) * 2) = (f16)v;
                }
            }
        }
        lgkm0();
        barrier_raw();
#pragma unroll
        for (int i = 0; i < 16; i++) {
            int ci = i * 512 + t;
            int row = ci >> 5, blk = ci & 31;
            int pblk = blk ^ (row & 31);
            f16x8 vle = *(const f16x8*)(smem + row * 512 + (pblk << 4));
            *(f16x8*)((f16*)Cp + (size_t)(r0 + row) * 512 + c0 + blk * 8) = vle;
        }
    } else {
        // fp32 out: scalar stores (16 lanes x 4B = full 64B lines; already coalescing-optimal)
#pragma unroll
        for (int nb = 0; nb < 4; nb++) {
            int col = c0 + wc + nb * 16 + lr;
            float b = bias[col];
#pragma unroll
            for (int m = 0; m < 8; m++) {
#pragma unroll
                for (int r = 0; r < 4; r++) {
                    float v = acc[m][nb][r] + b;
                    if (RELU) v = fmaxf(v, 0.0f);
                    size_t row = (size_t)(r0 + wr + m * 16 + lq * 4 + r);
                    ((float*)Cp)[row * 512 + col] = v;
                }
            }
        }
    }
}

// ---------------- K2: attention per (b,h,n). 1 wave/block. LDS-coalesced O store. ----------------
__global__ __launch_bounds__(64) void attn_kernel(const f16* __restrict__ q,
                                                  const f16* __restrict__ k,
                                                  const f16* __restrict__ v,
                                                  f16* __restrict__ out) {
    const int h = blockIdx.x, n = blockIdx.y, b = blockIdx.z;
    __shared__ f16 sQ[48 * 72];
    __shared__ f16 sK[48 * 72];
    __shared__ f16 sP[48 * 72];
    __shared__ f16 sVt[64 * 72];
    const int l = threadIdx.x, lr = l & 15, lq = l >> 4;
    const size_t rowstride = 256 * 512;
    const size_t base = ((size_t)(b * 48) * 256 + n) * 512 + h * 64;

    const int pr = l >> 3, pc = (l & 7) * 8;
#pragma unroll
    for (int pass = 0; pass < 6; pass++) {
        int row = pass * 8 + pr;
        size_t g = base + (size_t)row * rowstride + pc;
        f16x8 qv = *(const f16x8*)(q + g);
        f16x8 kv = *(const f16x8*)(k + g);
        f16x8 vv = *(const f16x8*)(v + g);
        *(f16x8*)&sQ[row * 72 + pc] = qv;
        *(f16x8*)&sK[row * 72 + pc] = kv;
#pragma unroll
        for (int jj = 0; jj < 8; jj++) sVt[(pc + jj) * 72 + row] = vv[jj];
    }
    {
        f16x8 z = {};
        *(f16x8*)&sVt[l * 72 + 48] = z;
        *(f16x8*)&sVt[l * 72 + 56] = z;
        if (l < 48) { *(f16x8*)&sP[l * 72 + 48] = z; *(f16x8*)&sP[l * 72 + 56] = z; }
    }
    __syncthreads();

    f32x4 s[3][3] = {};
#pragma unroll
    for (int ks = 0; ks < 2; ks++) {
        f16x8 aq[3], bk[3];
#pragma unroll
        for (int m = 0; m < 3; m++)  aq[m] = *(const f16x8*)&sQ[(m * 16 + lr) * 72 + ks * 32 + lq * 8];
#pragma unroll
        for (int nb = 0; nb < 3; nb++) bk[nb] = *(const f16x8*)&sK[(nb * 16 + lr) * 72 + ks * 32 + lq * 8];
#pragma unroll
        for (int m = 0; m < 3; m++)
#pragma unroll
            for (int nb = 0; nb < 3; nb++)
                s[m][nb] = __builtin_amdgcn_mfma_f32_16x16x32_f16(aq[m], bk[nb], s[m][nb], 0, 0, 0);
    }

#pragma unroll
    for (int m = 0; m < 3; m++) {
#pragma unroll
        for (int r = 0; r < 4; r++) {
            float a0 = s[m][0][r] * 0.125f, a1 = s[m][1][r] * 0.125f, a2 = s[m][2][r] * 0.125f;
            float mx = fmaxf(a0, fmaxf(a1, a2));
#pragma unroll
            for (int d = 1; d < 16; d <<= 1) mx = fmaxf(mx, __shfl_xor(mx, d));
            float e0 = __expf(a0 - mx), e1 = __expf(a1 - mx), e2 = __expf(a2 - mx);
            float sm = e0 + e1 + e2;
#pragma unroll
            for (int d = 1; d < 16; d <<= 1) sm += __shfl_xor(sm, d);
            float inv = 1.0f / sm;
            int row = m * 16 + lq * 4 + r;
            sP[row * 72 + 0  + lr] = (f16)(e0 * inv);
            sP[row * 72 + 16 + lr] = (f16)(e1 * inv);
            sP[row * 72 + 32 + lr] = (f16)(e2 * inv);
        }
    }
    __syncthreads();

    f32x4 o[3][4] = {};
#pragma unroll
    for (int ks = 0; ks < 2; ks++) {
        f16x8 ap[3], bvv[4];
#pragma unroll
        for (int m = 0; m < 3; m++)  ap[m] = *(const f16x8*)&sP[(m * 16 + lr) * 72 + ks * 32 + lq * 8];
#pragma unroll
        for (int nb = 0; nb < 4; nb++) bvv[nb] = *(const f16x8*)&sVt[(nb * 16 + lr) * 72 + ks * 32 + lq * 8];
#pragma unroll
        for (int m = 0; m < 3; m++)
#pragma unroll
            for (int nb = 0; nb < 4; nb++)
                o[m][nb] = __builtin_amdgcn_mfma_f32_16x16x32_f16(ap[m], bvv[nb], o[m][nb], 0, 0, 0);
    }

    // LDS-coalesced O store: stage [48 rows][128B] into sQ (free after QK^T), blk ^= (row&7)
    {
        char* so = (char*)sQ;
#pragma unroll
        for (int m = 0; m < 3; m++)
#pragma unroll
            for (int nb = 0; nb < 4; nb++)
#pragma unroll
                for (int r = 0; r < 4; r++) {
                    int row = m * 16 + lq * 4 + r;
                    int col = nb * 16 + lr;
                    int pblk = (col >> 3) ^ (row & 7);
                    *(f16*)(so + row * 128 + (pblk << 4) + (col & 7) * 2) = (f16)o[m][nb][r];
                }
        __syncthreads();
#pragma unroll
        for (int i = 0; i < 6; i++) {
            int ci = i * 64 + l;
            int row = ci >> 3, blk = ci & 7;
            int pblk = blk ^ (row & 7);
            f16x8 vle = *(const f16x8*)(so + row * 128 + (pblk << 4));
            *(f16x8*)(out + base + (size_t)row * rowstride + blk * 8) = vle;
        }
    }
}

// ---------------- launch ----------------
extern "C" void kernel_launch(void* const* d_in, const int* in_sizes, int n_in,
                              void* d_out, int out_size, void* d_ws, size_t ws_size,
                              hipStream_t stream) {
    const float* X    = (const float*)d_in[0];
    const float* STEP = (const float*)d_in[1];
    const float* STEQ = (const float*)d_in[2];
    const float* Wq   = (const float*)d_in[3];
    const float* bq   = (const float*)d_in[4];
    const float* Wk   = (const float*)d_in[5];
    const float* bk   = (const float*)d_in[6];
    const float* Wv   = (const float*)d_in[7];
    const float* bv   = (const float*)d_in[8];
    const float* W1   = (const float*)d_in[9];
    const float* b1   = (const float*)d_in[10];
    const float* W2   = (const float*)d_in[11];
    const float* b2   = (const float*)d_in[12];
    float* out = (float*)d_out;

    const size_t MROWS = 98304;           // B*TQ*N = 8*48*256
    const size_t MBUF  = MROWS * 512;
    f16* ws  = (f16*)d_ws;
    f16* Wqt = ws;                        // 512*512 each
    f16* Wkt = ws + 262144;
    f16* Wvt = ws + 524288;
    f16* W1t = ws + 786432;
    f16* W2t = ws + 1048576;
    f16* qb  = ws + 1310720;              // MBUF f16 each
    f16* kb  = qb + MBUF;
    f16* vb  = kb + MBUF;
    f16* hb  = kb;                        // FFN hidden reuses k buffer (after attn)

    wconv<<<dim3(16, 16, 5), 256, 0, stream>>>(Wq, Wk, Wv, W1, W2, ws);

    gemm_rs<<<768, 512, 0, stream>>>(STEQ, Wqt, bq, qb);
    gemm_rs<<<768, 512, 0, stream>>>(STEP, Wkt, bk, kb);
    gemm_rs<<<768, 512, 0, stream>>>(X,    Wvt, bv, vb);

    attn_kernel<<<dim3(8, 256, 8), 64, 0, stream>>>(qb, kb, vb, qb);

    gemm_8ph<true,  true ><<<768, 512, 0, stream>>>(qb, W1t, b1, hb);
    gemm_8ph<false, false><<<768, 512, 0, stream>>>(hb, W2t, b2, out);
}

// Round 23
// 569.816 us; speedup vs baseline: 1.2032x; 1.0174x over previous
//
#include <hip/hip_runtime.h>

typedef _Float16 f16;
typedef __fp16 hf2 __attribute__((ext_vector_type(2)));
typedef _Float16 f16x4 __attribute__((ext_vector_type(4)));
typedef _Float16 f16x8 __attribute__((ext_vector_type(8)));
typedef float f32x4 __attribute__((ext_vector_type(4)));

typedef const __attribute__((address_space(1))) unsigned int guint;
typedef __attribute__((address_space(3))) unsigned int luint;
__device__ __forceinline__ void gl_lds16(const void* g, void* l) {
    __builtin_amdgcn_global_load_lds((guint*)g, (luint*)l, 16, 0, 0);
}
template <int N>
__device__ __forceinline__ void vmwait() {
    if constexpr (N == 8)       asm volatile("s_waitcnt vmcnt(8)" ::: "memory");
    else if constexpr (N == 6)  asm volatile("s_waitcnt vmcnt(6)" ::: "memory");
    else if constexpr (N == 4)  asm volatile("s_waitcnt vmcnt(4)" ::: "memory");
    else                        asm volatile("s_waitcnt vmcnt(0)" ::: "memory");
}
__device__ __forceinline__ void barrier_raw() { __builtin_amdgcn_s_barrier(); __builtin_amdgcn_sched_barrier(0); }
__device__ __forceinline__ void lgkm0() { asm volatile("s_waitcnt lgkmcnt(0)" ::: "memory"); }

__device__ __forceinline__ f16x8 pack8(float4 x0, float4 x1) {
    hf2 p0 = __builtin_amdgcn_cvt_pkrtz(x0.x, x0.y);
    hf2 p1 = __builtin_amdgcn_cvt_pkrtz(x0.z, x0.w);
    hf2 p2 = __builtin_amdgcn_cvt_pkrtz(x1.x, x1.y);
    hf2 p3 = __builtin_amdgcn_cvt_pkrtz(x1.z, x1.w);
    f16x8 h;
    h[0] = (f16)p0[0]; h[1] = (f16)p0[1]; h[2] = (f16)p1[0]; h[3] = (f16)p1[1];
    h[4] = (f16)p2[0]; h[5] = (f16)p2[1]; h[6] = (f16)p3[0]; h[7] = (f16)p3[1];
    return h;
}

// ---------------- K0: convert + transpose 5 weight matrices (512x512) to f16 ----------------
__global__ __launch_bounds__(256) void wconv(const float* w0, const float* w1, const float* w2,
                                             const float* w3, const float* w4, f16* dst) {
    const float* src;
    switch (blockIdx.z) { case 0: src = w0; break; case 1: src = w1; break;
                          case 2: src = w2; break; case 3: src = w3; break; default: src = w4; }
    __shared__ float tile[32][33];
    int k0 = blockIdx.x * 32, n0 = blockIdx.y * 32;
    int t = threadIdx.x;
    int r = t >> 3, c4 = (t & 7) * 4;
    float4 v = *(const float4*)(src + (k0 + r) * 512 + n0 + c4);
    tile[r][c4 + 0] = v.x; tile[r][c4 + 1] = v.y; tile[r][c4 + 2] = v.z; tile[r][c4 + 3] = v.w;
    __syncthreads();
    f16x4 o;
    o[0] = (f16)tile[c4 + 0][r]; o[1] = (f16)tile[c4 + 1][r];
    o[2] = (f16)tile[c4 + 2][r]; o[3] = (f16)tile[c4 + 3][r];
    *(f16x4*)(dst + (size_t)blockIdx.z * 262144 + (n0 + r) * 512 + k0 + c4) = o;
}

// ---------------- K1a (QKV, fp32-A): merged q/k/v in one 2304-block launch ----------------
// Body identical to R20/R22-proven gemm_rs (8ph skeleton + reg-staged A conversion + LDS-coalesced
// epilogue). Block -> matrix: mid = wgid/768 (post-XCD-swizzle; 2304%8==0 keeps it bijective).
__global__ __launch_bounds__(512, 2) void gemm_qkv3(const float* __restrict__ A0, const float* __restrict__ A1,
                                                    const float* __restrict__ A2,
                                                    const f16* __restrict__ B0, const f16* __restrict__ B1,
                                                    const f16* __restrict__ B2,
                                                    const float* __restrict__ bias0, const float* __restrict__ bias1,
                                                    const float* __restrict__ bias2,
                                                    f16* __restrict__ C0, f16* __restrict__ C1,
                                                    f16* __restrict__ C2) {
    constexpr int BUFSZ = 32768;   // A f16 16KB + B f16 16KB
    __shared__ __align__(16) char smem[4 * BUFSZ];

    const int cpx = gridDim.x >> 3;               // 288
    const int orig = blockIdx.x;
    const int wgid = (orig & 7) * cpx + (orig >> 3);
    const int mid = wgid / 768;                   // matrix 0..2
    const int sub = wgid - mid * 768;
    const int by = sub & 1, bx = sub >> 1;
    const int r0 = bx * 256, c0 = by * 256;

    const float* A   = (mid == 0) ? A0 : (mid == 1) ? A1 : A2;
    const f16* Bt    = (mid == 0) ? B0 : (mid == 1) ? B1 : B2;
    const float* bias = (mid == 0) ? bias0 : (mid == 1) ? bias1 : bias2;
    f16* Cp          = (mid == 0) ? C0 : (mid == 1) ? C1 : C2;

    const int t = threadIdx.x, j = t & 63, w = t >> 6;
    const int lr = j & 15, lq = j >> 4;
    const int wr = (w >> 2) * 128, wc = (w & 3) * 64;

    const float* aS = A + (size_t)(r0 + (t >> 1)) * 512 + (t & 1) * 16;
    const int awRow = t >> 1;
    const int awS = (t >> 2) & 3;
    const int awc = (t & 1) * 2;
    const int aw0 = awRow * 64 + ((awc ^ awS) << 4);
    const int aw1 = awRow * 64 + (((awc + 1) ^ awS) << 4);

    const int srow = t >> 2;
    const int sblk = (t & 3) ^ ((t >> 3) & 3);
    const f16* bS = Bt + (size_t)(c0 + srow) * 512 + sblk * 8;
    const int dstT = t * 16;

    int aoff[8], boff[4];
#pragma unroll
    for (int m = 0; m < 8; m++) {
        int row = wr + m * 16 + lr;
        aoff[m] = row * 64 + ((lq ^ ((row >> 1) & 3)) << 4);
    }
#pragma unroll
    for (int nb = 0; nb < 4; nb++) {
        int row = wc + nb * 16 + lr;
        boff[nb] = 16384 + row * 64 + ((lq ^ ((row >> 1) & 3)) << 4);
    }

    f32x4 acc[8][4] = {};
    float4 rgA[4], rgB[4];

    auto loadTo = [&](int kt, float4* rg) {
        const float* p = aS + kt * 32;
        rg[0] = *(const float4*)p;
        rg[1] = *(const float4*)(p + 4);
        rg[2] = *(const float4*)(p + 8);
        rg[3] = *(const float4*)(p + 12);
    };
    auto writeA = [&](const float4* rg, int buf) {
        char* base = smem + buf * BUFSZ;
        *(f16x8*)(base + aw0) = pack8(rg[0], rg[1]);
        *(f16x8*)(base + aw1) = pack8(rg[2], rg[3]);
    };
    auto stageB = [&](int kt) {
        char* d = smem + (kt & 3) * BUFSZ + 16384 + dstT;
        const f16* s = bS + kt * 32;
        gl_lds16(s, d);
        gl_lds16(s + 65536, d + 8192);
    };

#define PHASE_A(kt, bfr)                                                    \
    do {                                                                    \
        const char* sb_ = smem + ((kt) & 3) * BUFSZ;                        \
        f16x8 afr[4];                                                       \
        _Pragma("unroll")                                                   \
        for (int nb = 0; nb < 4; nb++) bfr[nb] = *(const f16x8*)(sb_ + boff[nb]); \
        _Pragma("unroll")                                                   \
        for (int m = 0; m < 4; m++) afr[m] = *(const f16x8*)(sb_ + aoff[m]); \
        __builtin_amdgcn_s_setprio(1);                                      \
        _Pragma("unroll")                                                   \
        for (int m = 0; m < 4; m++)                                         \
            _Pragma("unroll")                                               \
            for (int nb = 0; nb < 4; nb++)                                  \
                acc[m][nb] = __builtin_amdgcn_mfma_f32_16x16x32_f16(afr[m], bfr[nb], acc[m][nb], 0, 0, 0); \
        __builtin_amdgcn_s_setprio(0);                                      \
    } while (0)

#define PHASE_B(kt, bfr)                                                    \
    do {                                                                    \
        const char* sb_ = smem + ((kt) & 3) * BUFSZ;                        \
        f16x8 afr2[4];                                                      \
        _Pragma("unroll")                                                   \
        for (int m = 0; m < 4; m++) afr2[m] = *(const f16x8*)(sb_ + aoff[m + 4]); \
        __builtin_amdgcn_s_setprio(1);                                      \
        _Pragma("unroll")                                                   \
        for (int m = 0; m < 4; m++)                                         \
            _Pragma("unroll")                                               \
            for (int nb = 0; nb < 4; nb++)                                  \
                acc[m + 4][nb] = __builtin_amdgcn_mfma_f32_16x16x32_f16(afr2[m], bfr[nb], acc[m + 4][nb], 0, 0, 0); \
        __builtin_amdgcn_s_setprio(0);                                      \
    } while (0)

    loadTo(0, rgA);
    stageB(0); stageB(1);
    loadTo(1, rgB);
    stageB(2);
    vmwait<8>();
    __builtin_amdgcn_sched_barrier(0);
    writeA(rgA, 0);
    lgkm0();
    barrier_raw();

#pragma unroll 1
    for (int k2 = 0; k2 < 8; ++k2) {
        {   // even sub-iter
            const int kt = 2 * k2;
            if (k2 <= 6) loadTo(kt + 2, rgA);
            if (k2 <= 6) vmwait<6>(); else vmwait<0>();
            __builtin_amdgcn_sched_barrier(0);
            writeA(rgB, (kt + 1) & 3);
            f16x8 bfr[4];
            PHASE_A(kt, bfr);
            barrier_raw();
            if (k2 <= 6) stageB(kt + 3);
            PHASE_B(kt, bfr);
            lgkm0();
            barrier_raw();
        }
        {   // odd sub-iter
            const int kt = 2 * k2 + 1;
            if (k2 <= 6) loadTo(kt + 2, rgB);
            if (k2 <= 6) vmwait<6>(); else vmwait<0>();
            __builtin_amdgcn_sched_barrier(0);
            if (k2 <= 6) writeA(rgA, (kt + 1) & 3);
            f16x8 bfr[4];
            PHASE_A(kt, bfr);
            barrier_raw();
            if (k2 <= 5) stageB(kt + 3);
            PHASE_B(kt, bfr);
            lgkm0();
            barrier_raw();
        }
    }
#undef PHASE_A
#undef PHASE_B

    // LDS-coalesced epilogue (R20-proven): [256 rows][512B], blk ^= (row&31)
#pragma unroll
    for (int nb = 0; nb < 4; nb++) {
        int col = wc + nb * 16 + lr;
        float b = bias[c0 + col];
#pragma unroll
        for (int m = 0; m < 8; m++) {
#pragma unroll
            for (int r = 0; r < 4; r++) {
                float v = fmaxf(acc[m][nb][r] + b, 0.0f);
                int row = wr + m * 16 + lq * 4 + r;
                int pblk = (col >> 3) ^ (row & 31);
                *(f16*)(smem + row * 512 + (pblk << 4) + (col & 7) * 2) = (f16)v;
            }
        }
    }
    lgkm0();
    barrier_raw();
#pragma unroll
    for (int i = 0; i < 16; i++) {
        int ci = i * 512 + t;
        int row = ci >> 5, blk = ci & 31;
        int pblk = blk ^ (row & 31);
        f16x8 vle = *(const f16x8*)(smem + row * 512 + (pblk << 4));
        *(f16x8*)(Cp + (size_t)(r0 + row) * 512 + c0 + blk * 8) = vle;
    }
}

// ---------------- K1b (FFN, f16-A): 8-phase counted-vmcnt GEMM ----------------
// O16 (f16 out): LDS-coalesced epilogue. !O16 (fp32 out): scalar epilogue (full 64B lines).
template <bool RELU, bool O16>
__global__ __launch_bounds__(512, 2) void gemm_8ph(const f16* __restrict__ A,
                                                   const f16* __restrict__ Bt,
                                                   const float* __restrict__ bias,
                                                   void* __restrict__ Cp) {
    constexpr int BUFSZ = 32768;
    __shared__ __align__(16) char smem[4 * BUFSZ];

    const int cpx = gridDim.x >> 3;
    const int orig = blockIdx.x;
    const int wgid = (orig & 7) * cpx + (orig >> 3);
    const int by = wgid & 1;
    const int bx = wgid >> 1;
    const int r0 = bx * 256, c0 = by * 256;

    const int t = threadIdx.x;
    const int j = t & 63, w = t >> 6;
    const int lr = j & 15, lq = j >> 4;
    const int wr = (w >> 2) * 128, wc = (w & 3) * 64;

    const int srow = t >> 2;
    const int sblk = (t & 3) ^ ((t >> 3) & 3);
    const f16* aS = A  + (size_t)(r0 + srow) * 512 + sblk * 8;
    const f16* bS = Bt + (size_t)(c0 + srow) * 512 + sblk * 8;
    const int dstT = t * 16;

    int aoff[8], boff[4];
#pragma unroll
    for (int m = 0; m < 8; m++) {
        int row = wr + m * 16 + lr;
        aoff[m] = row * 64 + ((lq ^ ((row >> 1) & 3)) << 4);
    }
#pragma unroll
    for (int nb = 0; nb < 4; nb++) {
        int row = wc + nb * 16 + lr;
        boff[nb] = 16384 + row * 64 + ((lq ^ ((row >> 1) & 3)) << 4);
    }

    f32x4 acc[8][4] = {};

    auto stageA = [&](int kt) {
        char* d = smem + (kt & 3) * BUFSZ + dstT;
        const f16* s = aS + kt * 32;
        gl_lds16(s, d);
        gl_lds16(s + 65536, d + 8192);
    };
    auto stageB = [&](int kt) {
        char* d = smem + (kt & 3) * BUFSZ + 16384 + dstT;
        const f16* s = bS + kt * 32;
        gl_lds16(s, d);
        gl_lds16(s + 65536, d + 8192);
    };

    stageA(0); stageB(0); stageA(1); stageB(1); stageA(2); stageB(2);

#pragma unroll 1
    for (int kt = 0; kt < 16; ++kt) {
        const char* sb = smem + (kt & 3) * BUFSZ;
        if (kt <= 13)      vmwait<8>();
        else if (kt == 14) vmwait<4>();
        else               vmwait<0>();
        barrier_raw();
        if (kt < 13) stageA(kt + 3);
        f16x8 bfr[4], afr[4];
#pragma unroll
        for (int nb = 0; nb < 4; nb++) bfr[nb] = *(const f16x8*)(sb + boff[nb]);
#pragma unroll
        for (int m = 0; m < 4; m++) afr[m] = *(const f16x8*)(sb + aoff[m]);
        __builtin_amdgcn_s_setprio(1);
#pragma unroll
        for (int m = 0; m < 4; m++)
#pragma unroll
            for (int nb = 0; nb < 4; nb++)
                acc[m][nb] = __builtin_amdgcn_mfma_f32_16x16x32_f16(afr[m], bfr[nb], acc[m][nb], 0, 0, 0);
        __builtin_amdgcn_s_setprio(0);
        barrier_raw();
        if (kt < 13) stageB(kt + 3);
        f16x8 afr2[4];
#pragma unroll
        for (int m = 0; m < 4; m++) afr2[m] = *(const f16x8*)(sb + aoff[m + 4]);
        __builtin_amdgcn_s_setprio(1);
#pragma unroll
        for (int m = 0; m < 4; m++)
#pragma unroll
            for (int nb = 0; nb < 4; nb++)
                acc[m + 4][nb] = __builtin_amdgcn_mfma_f32_16x16x32_f16(afr2[m], bfr[nb], acc[m + 4][nb], 0, 0, 0);
        __builtin_amdgcn_s_setprio(0);
    }

    if (O16) {
#pragma unroll
        for (int nb = 0; nb < 4; nb++) {
            int col = wc + nb * 16 + lr;
            float b = bias[c0 + col];
#pragma unroll
            for (int m = 0; m < 8; m++) {
#pragma unroll
                for (int r = 0; r < 4; r++) {
                    float v = acc[m][nb][r] + b;
                    if (RELU) v = fmaxf(v, 0.0f);
                    int row = wr + m * 16 + lq * 4 + r;
                    int pblk = (col >> 3) ^ (row & 31);
                    *(f16*)(smem + row * 512 + (pblk << 4) + (col & 7) * 2) = (f16)v;
                }
            }
        }
        lgkm0();
        barrier_raw();
#pragma unroll
        for (int i = 0; i < 16; i++) {
            int ci = i * 512 + t;
            int row = ci >> 5, blk = ci & 31;
            int pblk = blk ^ (row & 31);
            f16x8 vle = *(const f16x8*)(smem + row * 512 + (pblk << 4));
            *(f16x8*)((f16*)Cp + (size_t)(r0 + row) * 512 + c0 + blk * 8) = vle;
        }
    } else {
#pragma unroll
        for (int nb = 0; nb < 4; nb++) {
            int col = c0 + wc + nb * 16 + lr;
            float b = bias[col];
#pragma unroll
            for (int m = 0; m < 8; m++) {
#pragma unroll
                for (int r = 0; r < 4; r++) {
                    float v = acc[m][nb][r] + b;
                    if (RELU) v = fmaxf(v, 0.0f);
                    size_t row = (size_t)(r0 + wr + m * 16 + lq * 4 + r);
                    ((float*)Cp)[row * 512 + col] = v;
                }
            }
        }
    }
}

// ---------------- K2: attention per (b,h,n). 1 wave/block. LDS-coalesced O store. ----------------
__global__ __launch_bounds__(64) void attn_kernel(const f16* __restrict__ q,
                                                  const f16* __restrict__ k,
                                                  const f16* __restrict__ v,
                                                  f16* __restrict__ out) {
    const int h = blockIdx.x, n = blockIdx.y, b = blockIdx.z;
    __shared__ f16 sQ[48 * 72];
    __shared__ f16 sK[48 * 72];
    __shared__ f16 sP[48 * 72];
    __shared__ f16 sVt[64 * 72];
    const int l = threadIdx.x, lr = l & 15, lq = l >> 4;
    const size_t rowstride = 256 * 512;
    const size_t base = ((size_t)(b * 48) * 256 + n) * 512 + h * 64;

    const int pr = l >> 3, pc = (l & 7) * 8;
#pragma unroll
    for (int pass = 0; pass < 6; pass++) {
        int row = pass * 8 + pr;
        size_t g = base + (size_t)row * rowstride + pc;
        f16x8 qv = *(const f16x8*)(q + g);
        f16x8 kv = *(const f16x8*)(k + g);
        f16x8 vv = *(const f16x8*)(v + g);
        *(f16x8*)&sQ[row * 72 + pc] = qv;
        *(f16x8*)&sK[row * 72 + pc] = kv;
#pragma unroll
        for (int jj = 0; jj < 8; jj++) sVt[(pc + jj) * 72 + row] = vv[jj];
    }
    {
        f16x8 z = {};
        *(f16x8*)&sVt[l * 72 + 48] = z;
        *(f16x8*)&sVt[l * 72 + 56] = z;
        if (l < 48) { *(f16x8*)&sP[l * 72 + 48] = z; *(f16x8*)&sP[l * 72 + 56] = z; }
    }
    __syncthreads();

    f32x4 s[3][3] = {};
#pragma unroll
    for (int ks = 0; ks < 2; ks++) {
        f16x8 aq[3], bk[3];
#pragma unroll
        for (int m = 0; m < 3; m++)  aq[m] = *(const f16x8*)&sQ[(m * 16 + lr) * 72 + ks * 32 + lq * 8];
#pragma unroll
        for (int nb = 0; nb < 3; nb++) bk[nb] = *(const f16x8*)&sK[(nb * 16 + lr) * 72 + ks * 32 + lq * 8];
#pragma unroll
        for (int m = 0; m < 3; m++)
#pragma unroll
            for (int nb = 0; nb < 3; nb++)
                s[m][nb] = __builtin_amdgcn_mfma_f32_16x16x32_f16(aq[m], bk[nb], s[m][nb], 0, 0, 0);
    }

#pragma unroll
    for (int m = 0; m < 3; m++) {
#pragma unroll
        for (int r = 0; r < 4; r++) {
            float a0 = s[m][0][r] * 0.125f, a1 = s[m][1][r] * 0.125f, a2 = s[m][2][r] * 0.125f;
            float mx = fmaxf(a0, fmaxf(a1, a2));
#pragma unroll
            for (int d = 1; d < 16; d <<= 1) mx = fmaxf(mx, __shfl_xor(mx, d));
            float e0 = __expf(a0 - mx), e1 = __expf(a1 - mx), e2 = __expf(a2 - mx);
            float sm = e0 + e1 + e2;
#pragma unroll
            for (int d = 1; d < 16; d <<= 1) sm += __shfl_xor(sm, d);
            float inv = 1.0f / sm;
            int row = m * 16 + lq * 4 + r;
            sP[row * 72 + 0  + lr] = (f16)(e0 * inv);
            sP[row * 72 + 16 + lr] = (f16)(e1 * inv);
            sP[row * 72 + 32 + lr] = (f16)(e2 * inv);
        }
    }
    __syncthreads();

    f32x4 o[3][4] = {};
#pragma unroll
    for (int ks = 0; ks < 2; ks++) {
        f16x8 ap[3], bvv[4];
#pragma unroll
        for (int m = 0; m < 3; m++)  ap[m] = *(const f16x8*)&sP[(m * 16 + lr) * 72 + ks * 32 + lq * 8];
#pragma unroll
        for (int nb = 0; nb < 4; nb++) bvv[nb] = *(const f16x8*)&sVt[(nb * 16 + lr) * 72 + ks * 32 + lq * 8];
#pragma unroll
        for (int m = 0; m < 3; m++)
#pragma unroll
            for (int nb = 0; nb < 4; nb++)
                o[m][nb] = __builtin_amdgcn_mfma_f32_16x16x32_f16(ap[m], bvv[nb], o[m][nb], 0, 0, 0);
    }

    // LDS-coalesced O store: stage [48 rows][128B] into sQ (free after QK^T), blk ^= (row&7)
    {
        char* so = (char*)sQ;
#pragma unroll
        for (int m = 0; m < 3; m++)
#pragma unroll
            for (int nb = 0; nb < 4; nb++)
#pragma unroll
                for (int r = 0; r < 4; r++) {
                    int row = m * 16 + lq * 4 + r;
                    int col = nb * 16 + lr;
                    int pblk = (col >> 3) ^ (row & 7);
                    *(f16*)(so + row * 128 + (pblk << 4) + (col & 7) * 2) = (f16)o[m][nb][r];
                }
        __syncthreads();
#pragma unroll
        for (int i = 0; i < 6; i++) {
            int ci = i * 64 + l;
            int row = ci >> 3, blk = ci & 7;
            int pblk = blk ^ (row & 7);
            f16x8 vle = *(const f16x8*)(so + row * 128 + (pblk << 4));
            *(f16x8*)(out + base + (size_t)row * rowstride + blk * 8) = vle;
        }
    }
}

// ---------------- launch ----------------
extern "C" void kernel_launch(void* const* d_in, const int* in_sizes, int n_in,
                              void* d_out, int out_size, void* d_ws, size_t ws_size,
                              hipStream_t stream) {
    const float* X    = (const float*)d_in[0];
    const float* STEP = (const float*)d_in[1];
    const float* STEQ = (const float*)d_in[2];
    const float* Wq   = (const float*)d_in[3];
    const float* bq   = (const float*)d_in[4];
    const float* Wk   = (const float*)d_in[5];
    const float* bk   = (const float*)d_in[6];
    const float* Wv   = (const float*)d_in[7];
    const float* bv   = (const float*)d_in[8];
    const float* W1   = (const float*)d_in[9];
    const float* b1   = (const float*)d_in[10];
    const float* W2   = (const float*)d_in[11];
    const float* b2   = (const float*)d_in[12];
    float* out = (float*)d_out;

    const size_t MROWS = 98304;           // B*TQ*N = 8*48*256
    const size_t MBUF  = MROWS * 512;
    f16* ws  = (f16*)d_ws;
    f16* Wqt = ws;                        // 512*512 each
    f16* Wkt = ws + 262144;
    f16* Wvt = ws + 524288;
    f16* W1t = ws + 786432;
    f16* W2t = ws + 1048576;
    f16* qb  = ws + 1310720;              // MBUF f16 each
    f16* kb  = qb + MBUF;
    f16* vb  = kb + MBUF;
    f16* hb  = kb;                        // FFN hidden reuses k buffer (after attn)

    wconv<<<dim3(16, 16, 5), 256, 0, stream>>>(Wq, Wk, Wv, W1, W2, ws);

    gemm_qkv3<<<2304, 512, 0, stream>>>(STEQ, STEP, X, Wqt, Wkt, Wvt, bq, bk, bv, qb, kb, vb);

    attn_kernel<<<dim3(8, 256, 8), 64, 0, stream>>>(qb, kb, vb, qb);

    gemm_8ph<true,  true ><<<768, 512, 0, stream>>>(qb, W1t, b1, hb);
    gemm_8ph<false, false><<<768, 512, 0, stream>>>(hb, W2t, b2, out);
}